// Round 1
// baseline (1095.601 us; speedup 1.0000x reference)
//
#include <hip/hip_runtime.h>
#include <math.h>

#define DEV __device__ __forceinline__

typedef __attribute__((ext_vector_type(8))) short short8;
typedef __attribute__((ext_vector_type(4))) float floatx4;
typedef unsigned int u32;
typedef unsigned short u16;

DEV float gelu_f(float v) { return 0.5f * v * (1.0f + erff(v * 0.70710678118654752f)); }
DEV float softplus_f(float v) { return v > 15.0f ? v : log1pf(expf(v)); }

DEV u16 f2bf(float v) {
    u32 u = __float_as_uint(v);
    return (u16)((u + 0x7fffu + ((u >> 16) & 1u)) >> 16);
}

DEV void gload_lds16(const void* g, void* l) {
    __builtin_amdgcn_global_load_lds((const __attribute__((address_space(1))) u32*)g,
                                     (__attribute__((address_space(3))) u32*)l, 16, 0, 0);
}

// ---------------- ws layout ----------------
// float offsets
#define WS_A(j)     ((j) * 1040)
#define WS_KBUF     4160                      // 256 x 256 fp32 circulant kernels
#define WS_P        (4160 + 65536)            // 4x256 channel sums
#define WS_S        (WS_P + 1024)             // 4x256 sigmoid scales
// byte offsets
#define Y0_B        286976u                   // y bf16 [b][c][h][w], 134217728 B
#define AW0_B       134504704u                // A_w bf16 [b][o][c],  524288 B
#define CIRC0_B     135028992u                // circulants bf16 [256][256][256], 33554432 B
#define XB0_B       168583424u                // x bf16 (ch<128 transposed), 134217728 B
#define YT0_B       135028992u                // y^T bf16 [b][p][c] — aliases circ+xb (dead after gate)

struct MlpW { const float *w1, *b1, *w2, *b2, *w3, *b3; };

// ---------------- 1. tiny MLPs ----------------
__global__ void mlp_kernel(MlpW a0, MlpW a1, MlpW a2, MlpW a3, float* ws) {
    int j = blockIdx.x;
    MlpW m = (j == 0) ? a0 : (j == 1) ? a1 : (j == 2) ? a2 : a3;
    int n = (j == 1 || j == 3) ? 128 : 129;
    int i = threadIdx.x;
    if (i >= n) return;
    float g;
    if (j == 1 || j == 3) g = -1.0f + 2.0f * i / 127.0f;
    else                  g = 2.0f * i / 256.0f - 1.0f;
    float h1[64], h2[64];
    for (int k = 0; k < 64; k++) h1[k] = gelu_f(g * m.w1[k] + m.b1[k]);
    for (int q = 0; q < 64; q++) {
        float acc = m.b2[q];
        for (int k = 0; k < 64; k++) acc += h1[k] * m.w2[q * 64 + k];
        h2[q] = gelu_f(acc);
    }
    float* outp = ws + WS_A(j) + i * 8;
    for (int r = 0; r < 8; r++) {
        float acc = m.b3[r];
        for (int k = 0; k < 64; k++) acc += h2[k] * m.w3[r * 64 + k];
        outp[r] = acc;
    }
}

// ---------------- 2. gates -> circulant kernel vectors (fp32) ----------------
__global__ void gatek_kernel(float* ws) {
    int br = blockIdx.x >> 7, c = blockIdx.x & 127;
    const float* A = ws + WS_A(br == 0 ? 0 : 2);
    const float* B = ws + WS_A(br == 0 ? 1 : 3);
    __shared__ float G[129];
    int t = threadIdx.x;
    if (t < 129) {
        float acc = 0.f;
        for (int r = 0; r < 8; r++) acc += A[t * 8 + r] * B[c * 8 + r];
        G[t] = softplus_f(acc) * 0.35355339059327373f;
    }
    __syncthreads();
    float g0 = G[0], g128 = G[128];
    float acc = g0 + ((t & 1) ? -g128 : g128);
    for (int f = 1; f < 128; f++) {
        int idx = (f * t) & 255;
        acc += 2.0f * G[f] * cosf(idx * 0.02454369260617026f);
    }
    ws[WS_KBUF + blockIdx.x * 256 + t] = acc * (1.0f / 256.0f);
}

// ---------------- 3. materialize circulant matrices (bf16) ----------------
__global__ void circmat(const float* __restrict__ ws, u16* __restrict__ circ) {
    int mi = blockIdx.x, t = threadIdx.x;
    __shared__ float kl[256];
    kl[t] = ws[WS_KBUF + mi * 256 + t];
    __syncthreads();
    u16* M = circ + (size_t)mi * 65536u;
    for (int it = 0; it < 32; it++) {
        int e = it * 2048 + t * 8;
        int i = e >> 8, j = e & 255;
        u16 tmp[8];
#pragma unroll
        for (int jj = 0; jj < 8; jj++) tmp[jj] = f2bf(kl[(i - j - jj) & 255]);
        *(uint4*)&M[e] = *(uint4*)tmp;
    }
}

// ---------------- 4. prep: x fp32 -> bf16 (ch<128 transposed [w][h]) ----------------
__global__ void prep(const float* __restrict__ x, u16* __restrict__ xb) {
    int tile = blockIdx.x;          // 0..15
    int mat = blockIdx.y;           // 0..1023
    int t = threadIdx.x;
    const float* xm = x + (size_t)mat * 65536u;
    u16* xo = xb + (size_t)mat * 65536u;
    __shared__ float lt[64][65];
    if ((mat & 255) >= 128) {       // WC half: straight cast
        int base = tile * 4096 + t * 16;
#pragma unroll
        for (int q = 0; q < 4; q++) {
            float4 v = *(const float4*)&xm[base + q * 4];
            ushort4 o; o.x = f2bf(v.x); o.y = f2bf(v.y); o.z = f2bf(v.z); o.w = f2bf(v.w);
            *(ushort4*)&xo[base + q * 4] = o;
        }
    } else {                        // HC half: 64x64 tiled transpose
        int w0 = (tile & 3) * 64, h0 = (tile >> 2) * 64;
        int rh = t >> 2, cc = (t & 3) * 16;
#pragma unroll
        for (int q = 0; q < 4; q++) {
            float4 v = *(const float4*)&xm[(h0 + rh) * 256 + w0 + cc + q * 4];
            lt[rh][cc + q * 4 + 0] = v.x; lt[rh][cc + q * 4 + 1] = v.y;
            lt[rh][cc + q * 4 + 2] = v.z; lt[rh][cc + q * 4 + 3] = v.w;
        }
        __syncthreads();
        u16 tmp[16];
#pragma unroll
        for (int j = 0; j < 16; j++) tmp[j] = f2bf(lt[cc + j][rh]);
#pragma unroll
        for (int q = 0; q < 4; q++)
            *(ushort4*)&xo[(w0 + rh) * 256 + h0 + cc + q * 4] = *(ushort4*)&tmp[q * 4];
    }
}

// ---------------- 5. gating GEMMs (bf16 MFMA, 2-phase dbuf + counted vmcnt) ----------------
// HC (br=0): Y = M_c @ X    (A = circulant rows m, B = x^T rows n)
// WC (br=1): Y = X @ M_c    (A = x rows m,         B = circulant rows n)
__global__ __launch_bounds__(256) void gate_gemm(
    const u16* __restrict__ xb, const u16* __restrict__ circ,
    u16* __restrict__ y, float* __restrict__ ws)
{
    const int tile = blockIdx.x, c = blockIdx.y, zb = blockIdx.z;
    const int b = zb >> 1, br = zb & 1;
    const int m0 = (tile >> 1) * 128, n0 = (tile & 1) * 128;
    const int t = threadIdx.x, lane = t & 63, w = t >> 6;
    const int ch = br * 128 + c;

    const u16* Mbase = circ + (size_t)ch * 65536u;
    const u16* Xbase = xb + (size_t)(b * 256 + ch) * 65536u;
    const int rM0 = br ? n0 : m0;
    const int rX0 = br ? m0 : n0;

    __shared__ u16 ldsM[2][4096];
    __shared__ u16 ldsX[2][4096];

    const int s1 = t + 256;
    const int kq0 = t >> 7, r0s = t & 127;
    const int kq1 = s1 >> 7, r1s = s1 & 127;
    const u16* gM0 = Mbase + (rM0 + r0s) * 256 + kq0 * 8;
    const u16* gM1 = Mbase + (rM0 + r1s) * 256 + kq1 * 8;
    const u16* gX0 = Xbase + (rX0 + r0s) * 256 + kq0 * 8;
    const u16* gX1 = Xbase + (rX0 + r1s) * 256 + kq1 * 8;
    const int ldst = (t & 192) * 8;      // wave-uniform LDS dest base (u16)

    floatx4 acc[4][4];
#pragma unroll
    for (int i = 0; i < 4; i++)
#pragma unroll
        for (int j = 0; j < 4; j++) acc[i][j] = (floatx4){0.f, 0.f, 0.f, 0.f};

    const int wm = (w & 1) * 64, wn = (w >> 1) * 64;
    const int fr = lane & 15, fq = lane >> 4;
    const u16* aBuf0 = br ? &ldsX[0][0] : &ldsM[0][0];
    const u16* bBuf0 = br ? &ldsM[0][0] : &ldsX[0][0];
    const u16* aBuf1 = br ? &ldsX[1][0] : &ldsM[1][0];
    const u16* bBuf1 = br ? &ldsM[1][0] : &ldsX[1][0];

    auto stage = [&](u16* dM, u16* dX) {
        gload_lds16(gM0, dM); gload_lds16(gM1, dM + 2048);
        gload_lds16(gX0, dX); gload_lds16(gX1, dX + 2048);
        gM0 += 32; gM1 += 32; gX0 += 32; gX1 += 32;
    };
    auto compute = [&](const u16* Ab, const u16* Bb) {
        short8 aF[4], bF[4];
#pragma unroll
        for (int i = 0; i < 4; i++) aF[i] = *(const short8*)&Ab[(fq * 128 + wm + i * 16 + fr) * 8];
#pragma unroll
        for (int j = 0; j < 4; j++) bF[j] = *(const short8*)&Bb[(fq * 128 + wn + j * 16 + fr) * 8];
#pragma unroll
        for (int i = 0; i < 4; i++)
#pragma unroll
            for (int j = 0; j < 4; j++)
                acc[i][j] = __builtin_amdgcn_mfma_f32_16x16x32_bf16(aF[i], bF[j], acc[i][j], 0, 0, 0);
    };

    stage(&ldsM[0][ldst], &ldsX[0][ldst]);              // k=0 -> buf0
#pragma unroll
    for (int kk = 0; kk < 4; kk++) {
        stage(&ldsM[1][ldst], &ldsX[1][ldst]);          // k+32 -> buf1
        asm volatile("s_waitcnt vmcnt(4)\n\ts_barrier" ::: "memory");
        compute(aBuf0, bBuf0);                          // buf0
        asm volatile("s_barrier" ::: "memory");
        if (kk < 3) {
            stage(&ldsM[0][ldst], &ldsX[0][ldst]);      // k+64 -> buf0
            asm volatile("s_waitcnt vmcnt(4)\n\ts_barrier" ::: "memory");
        } else {
            asm volatile("s_waitcnt vmcnt(0)\n\ts_barrier" ::: "memory");
        }
        compute(aBuf1, bBuf1);                          // buf1
        asm volatile("s_barrier" ::: "memory");
    }

    // epilogue: bf16 y + channel sum
    size_t ybase = (size_t)(b * 256 + ch) * 65536u;
    float lsum = 0.f;
#pragma unroll
    for (int i = 0; i < 4; i++)
#pragma unroll
        for (int r = 0; r < 4; r++) {
            int row = m0 + wm + i * 16 + fq * 4 + r;
            size_t rb = ybase + (size_t)row * 256;
#pragma unroll
            for (int j = 0; j < 4; j++) {
                float v = acc[i][j][r];
                lsum += v;
                y[rb + n0 + wn + j * 16 + fr] = f2bf(v);
            }
        }
    for (int off = 32; off; off >>= 1) lsum += __shfl_down(lsum, off, 64);
    __shared__ float wsum[4];
    if (lane == 0) wsum[w] = lsum;
    __syncthreads();
    if (t == 0) atomicAdd(ws + WS_P + b * 256 + ch, wsum[0] + wsum[1] + wsum[2] + wsum[3]);
}

// ---------------- 6. attention scales + A_w = lc_w * s (bf16) ----------------
__global__ void attn_kernel(const float* __restrict__ ca_w1, const float* __restrict__ ca_b1,
                            const float* __restrict__ ca_dw, const float* __restrict__ ca_db,
                            const float* __restrict__ lc_w, float* ws, u16* __restrict__ aw) {
    int b = blockIdx.x, o = threadIdx.x;
    __shared__ float pm[256];
    __shared__ float sl[256];
    pm[o] = ws[WS_P + b * 256 + o] * (1.0f / 65536.0f);
    __syncthreads();
    float acc = ca_b1[o];
    for (int c2 = 0; c2 < 256; c2++) acc += ca_w1[o * 256 + c2] * pm[c2];
    float q = gelu_f(acc);
    float tv = q * ca_dw[o * 9 + 4] + ca_db[o];
    float s = 1.0f / (1.0f + expf(-tv));
    ws[WS_S + b * 256 + o] = s;
    sl[o] = s;
    __syncthreads();
    u16* awb = aw + b * 65536;
    for (int row = 0; row < 256; row++)
        awb[row * 256 + o] = f2bf(lc_w[row * 256 + o] * sl[o]);
}

// ---------------- 7. y -> y^T (bf16) ----------------
__global__ void ytrans(const u16* __restrict__ y, u16* __restrict__ yt) {
    int pt = blockIdx.x, ct = blockIdx.y, b = blockIdx.z;
    const u16* yb = y + (size_t)b * 16777216u;
    u16* ytb = yt + (size_t)b * 16777216u;
    int p0 = pt * 64, c0 = ct * 64;
    __shared__ u16 lt[64][74];   // 37-dword pitch: conflict-lite
    int t = threadIdx.x;
    int rr = t >> 3, pc = (t & 7) * 8;
#pragma unroll
    for (int it = 0; it < 2; it++) {
        int row = rr + it * 32;
        ushort4 a0 = *(const ushort4*)&yb[(size_t)(c0 + row) * 65536u + p0 + pc];
        ushort4 a1 = *(const ushort4*)&yb[(size_t)(c0 + row) * 65536u + p0 + pc + 4];
        lt[row][pc + 0] = a0.x; lt[row][pc + 1] = a0.y; lt[row][pc + 2] = a0.z; lt[row][pc + 3] = a0.w;
        lt[row][pc + 4] = a1.x; lt[row][pc + 5] = a1.y; lt[row][pc + 6] = a1.z; lt[row][pc + 7] = a1.w;
    }
    __syncthreads();
#pragma unroll
    for (int it = 0; it < 2; it++) {
        int row = rr + it * 32;       // p-rel
        u16 tmp[8];
#pragma unroll
        for (int j = 0; j < 8; j++) tmp[j] = lt[pc + j][row];
        *(uint4*)&ytb[(size_t)(p0 + row) * 256 + c0 + pc] = *(uint4*)tmp;
    }
}

// ---------------- 8. 1x1 conv GEMM + BN + GELU + residual (2-phase dbuf) ----------------
__global__ __launch_bounds__(256) void conv_gemm(
    const float* __restrict__ x, const u16* __restrict__ aw, const u16* __restrict__ yt,
    const float* __restrict__ bn_g, const float* __restrict__ bn_b,
    const float* __restrict__ bn_m, const float* __restrict__ bn_v,
    float* __restrict__ out)
{
    const int m0 = blockIdx.x * 128;      // o
    const int n0 = blockIdx.y * 128;      // p
    const int b = blockIdx.z;
    const int t = threadIdx.x, lane = t & 63, w = t >> 6;

    const u16* Abase = aw + (size_t)b * 65536u;
    const u16* Bbase = yt + (size_t)b * 16777216u;

    __shared__ u16 ldsA[2][4096];
    __shared__ u16 ldsB[2][4096];

    const int s1 = t + 256;
    const int kq0 = t >> 7, r0s = t & 127;
    const int kq1 = s1 >> 7, r1s = s1 & 127;
    const u16* gA0 = Abase + (m0 + r0s) * 256 + kq0 * 8;
    const u16* gA1 = Abase + (m0 + r1s) * 256 + kq1 * 8;
    const u16* gB0 = Bbase + (size_t)(n0 + r0s) * 256 + kq0 * 8;
    const u16* gB1 = Bbase + (size_t)(n0 + r1s) * 256 + kq1 * 8;
    const int ldst = (t & 192) * 8;      // wave-uniform LDS dest base (u16)

    floatx4 acc[4][4];
#pragma unroll
    for (int i = 0; i < 4; i++)
#pragma unroll
        for (int j = 0; j < 4; j++) acc[i][j] = (floatx4){0.f, 0.f, 0.f, 0.f};

    const int wm = (w & 1) * 64, wn = (w >> 1) * 64;
    const int fr = lane & 15, fq = lane >> 4;

    auto stage = [&](u16* dA, u16* dB) {
        gload_lds16(gA0, dA); gload_lds16(gA1, dA + 2048);
        gload_lds16(gB0, dB); gload_lds16(gB1, dB + 2048);
        gA0 += 32; gA1 += 32; gB0 += 32; gB1 += 32;
    };
    auto compute = [&](const u16* Ab, const u16* Bb) {
        short8 aF[4], bF[4];
#pragma unroll
        for (int i = 0; i < 4; i++) aF[i] = *(const short8*)&Ab[(fq * 128 + wm + i * 16 + fr) * 8];
#pragma unroll
        for (int j = 0; j < 4; j++) bF[j] = *(const short8*)&Bb[(fq * 128 + wn + j * 16 + fr) * 8];
#pragma unroll
        for (int i = 0; i < 4; i++)
#pragma unroll
            for (int j = 0; j < 4; j++)
                acc[i][j] = __builtin_amdgcn_mfma_f32_16x16x32_bf16(aF[i], bF[j], acc[i][j], 0, 0, 0);
    };

    stage(&ldsA[0][ldst], &ldsB[0][ldst]);              // k=0 -> buf0
#pragma unroll
    for (int kk = 0; kk < 4; kk++) {
        stage(&ldsA[1][ldst], &ldsB[1][ldst]);          // k+32 -> buf1
        asm volatile("s_waitcnt vmcnt(4)\n\ts_barrier" ::: "memory");
        compute(&ldsA[0][0], &ldsB[0][0]);              // buf0
        asm volatile("s_barrier" ::: "memory");
        if (kk < 3) {
            stage(&ldsA[0][ldst], &ldsB[0][ldst]);      // k+64 -> buf0
            asm volatile("s_waitcnt vmcnt(4)\n\ts_barrier" ::: "memory");
        } else {
            asm volatile("s_waitcnt vmcnt(0)\n\ts_barrier" ::: "memory");
        }
        compute(&ldsA[1][0], &ldsB[1][0]);              // buf1
        asm volatile("s_barrier" ::: "memory");
    }

#pragma unroll
    for (int i = 0; i < 4; i++)
#pragma unroll
        for (int r = 0; r < 4; r++) {
            int o = m0 + wm + i * 16 + fq * 4 + r;
            float inv = bn_g[o] * rsqrtf(bn_v[o] + 1e-5f);
            float beta = bn_b[o] - bn_m[o] * inv;
            size_t rowb = (size_t)(b * 256 + o) * 65536u;
#pragma unroll
            for (int j = 0; j < 4; j++) {
                int p = n0 + wn + j * 16 + fr;
                float v = acc[i][j][r];
                out[rowb + p] = x[rowb + p] + gelu_f(v * inv + beta);
            }
        }
}

extern "C" void kernel_launch(void* const* d_in, const int* in_sizes, int n_in,
                              void* d_out, int out_size, void* d_ws, size_t ws_size,
                              hipStream_t stream) {
    const float* x = (const float*)d_in[0];
    MlpW m[4];
    for (int j = 0; j < 4; j++) {
        m[j].w1 = (const float*)d_in[1 + 6 * j + 0];
        m[j].b1 = (const float*)d_in[1 + 6 * j + 1];
        m[j].w2 = (const float*)d_in[1 + 6 * j + 2];
        m[j].b2 = (const float*)d_in[1 + 6 * j + 3];
        m[j].w3 = (const float*)d_in[1 + 6 * j + 4];
        m[j].b3 = (const float*)d_in[1 + 6 * j + 5];
    }
    const float* ca_w1 = (const float*)d_in[25];
    const float* ca_b1 = (const float*)d_in[26];
    const float* ca_dw = (const float*)d_in[27];
    const float* ca_db = (const float*)d_in[28];
    const float* lc_w  = (const float*)d_in[29];
    const float* bn_g  = (const float*)d_in[30];
    const float* bn_b  = (const float*)d_in[31];
    const float* bn_m  = (const float*)d_in[32];
    const float* bn_v  = (const float*)d_in[33];

    char* wsb = (char*)d_ws;
    float* ws = (float*)d_ws;
    u16* ybf  = (u16*)(wsb + Y0_B);
    u16* aw   = (u16*)(wsb + AW0_B);
    u16* circ = (u16*)(wsb + CIRC0_B);
    u16* xbb  = (u16*)(wsb + XB0_B);
    u16* yt   = (u16*)(wsb + YT0_B);
    float* out = (float*)d_out;

    hipLaunchKernelGGL(mlp_kernel, dim3(4), dim3(256), 0, stream, m[0], m[1], m[2], m[3], ws);
    hipLaunchKernelGGL(gatek_kernel, dim3(256), dim3(256), 0, stream, ws);
    hipLaunchKernelGGL(circmat, dim3(256), dim3(256), 0, stream, ws, circ);
    hipLaunchKernelGGL(prep, dim3(16, 1024), dim3(256), 0, stream, x, xbb);
    hipMemsetAsync(ws + WS_P, 0, 1024 * sizeof(float), stream);
    hipLaunchKernelGGL(gate_gemm, dim3(4, 128, 8), dim3(256), 0, stream, xbb, circ, ybf, ws);
    hipLaunchKernelGGL(attn_kernel, dim3(4), dim3(256), 0, stream,
                       ca_w1, ca_b1, ca_dw, ca_db, lc_w, ws, aw);
    hipLaunchKernelGGL(ytrans, dim3(1024, 4, 4), dim3(256), 0, stream, ybf, yt);
    hipLaunchKernelGGL(conv_gemm, dim3(2, 512, 4), dim3(256), 0, stream,
                       x, aw, yt, bn_g, bn_b, bn_m, bn_v, out);
}

// Round 3
// 1043.354 us; speedup vs baseline: 1.0501x; 1.0501x over previous
//
#include <hip/hip_runtime.h>
#include <math.h>

#define DEV __device__ __forceinline__

typedef __attribute__((ext_vector_type(8))) short short8;
typedef __attribute__((ext_vector_type(4))) float floatx4;
typedef unsigned int u32;
typedef unsigned short u16;

DEV float gelu_f(float v) { return 0.5f * v * (1.0f + erff(v * 0.70710678118654752f)); }
DEV float softplus_f(float v) { return v > 15.0f ? v : log1pf(expf(v)); }

DEV u16 f2bf(float v) {
    u32 u = __float_as_uint(v);
    return (u16)((u + 0x7fffu + ((u >> 16) & 1u)) >> 16);
}

DEV void gload_lds16(const void* g, void* l) {
    __builtin_amdgcn_global_load_lds((const __attribute__((address_space(1))) u32*)g,
                                     (__attribute__((address_space(3))) u32*)l, 16, 0, 0);
}

// ---------------- ws layout ----------------
// float offsets
#define WS_A(j)     ((j) * 1040)
#define WS_KBUF     4160                      // 256 x 256 fp32 circulant kernels
#define WS_P        (4160 + 65536)            // 4x256 channel sums
#define WS_S        (WS_P + 1024)             // 4x256 sigmoid scales
// byte offsets
#define Y0_B        286976u                   // y bf16 [b][c][h][w], 134217728 B
#define AW0_B       134504704u                // A_w bf16 [b][o][c],  524288 B
#define CIRC0_B     135028992u                // circulants bf16 [256][256][256], 33554432 B
#define XB0_B       168583424u                // x bf16 (ch<128 transposed), 134217728 B
#define YT0_B       135028992u                // y^T bf16 [b][p][c] — aliases circ+xb (dead after gate)

struct MlpW { const float *w1, *b1, *w2, *b2, *w3, *b3; };

// ---------------- 1. tiny MLPs ----------------
__global__ void mlp_kernel(MlpW a0, MlpW a1, MlpW a2, MlpW a3, float* ws) {
    int j = blockIdx.x;
    MlpW m = (j == 0) ? a0 : (j == 1) ? a1 : (j == 2) ? a2 : a3;
    int n = (j == 1 || j == 3) ? 128 : 129;
    int i = threadIdx.x;
    if (i >= n) return;
    float g;
    if (j == 1 || j == 3) g = -1.0f + 2.0f * i / 127.0f;
    else                  g = 2.0f * i / 256.0f - 1.0f;
    float h1[64], h2[64];
    for (int k = 0; k < 64; k++) h1[k] = gelu_f(g * m.w1[k] + m.b1[k]);
    for (int q = 0; q < 64; q++) {
        float acc = m.b2[q];
        for (int k = 0; k < 64; k++) acc += h1[k] * m.w2[q * 64 + k];
        h2[q] = gelu_f(acc);
    }
    float* outp = ws + WS_A(j) + i * 8;
    for (int r = 0; r < 8; r++) {
        float acc = m.b3[r];
        for (int k = 0; k < 64; k++) acc += h2[k] * m.w3[r * 64 + k];
        outp[r] = acc;
    }
}

// ---------------- 2. gates -> circulant kernel vectors (fp32) ----------------
__global__ void gatek_kernel(float* ws) {
    int br = blockIdx.x >> 7, c = blockIdx.x & 127;
    const float* A = ws + WS_A(br == 0 ? 0 : 2);
    const float* B = ws + WS_A(br == 0 ? 1 : 3);
    __shared__ float G[129];
    int t = threadIdx.x;
    if (t < 129) {
        float acc = 0.f;
        for (int r = 0; r < 8; r++) acc += A[t * 8 + r] * B[c * 8 + r];
        G[t] = softplus_f(acc) * 0.35355339059327373f;
    }
    __syncthreads();
    float g0 = G[0], g128 = G[128];
    float acc = g0 + ((t & 1) ? -g128 : g128);
    for (int f = 1; f < 128; f++) {
        int idx = (f * t) & 255;
        acc += 2.0f * G[f] * cosf(idx * 0.02454369260617026f);
    }
    ws[WS_KBUF + blockIdx.x * 256 + t] = acc * (1.0f / 256.0f);
}

// ---------------- 3. materialize circulant matrices (bf16) ----------------
__global__ void circmat(const float* __restrict__ ws, u16* __restrict__ circ) {
    int mi = blockIdx.x, t = threadIdx.x;
    __shared__ float kl[256];
    kl[t] = ws[WS_KBUF + mi * 256 + t];
    __syncthreads();
    u16* M = circ + (size_t)mi * 65536u;
    for (int it = 0; it < 32; it++) {
        int e = it * 2048 + t * 8;
        int i = e >> 8, j = e & 255;
        u16 tmp[8];
#pragma unroll
        for (int jj = 0; jj < 8; jj++) tmp[jj] = f2bf(kl[(i - j - jj) & 255]);
        *(uint4*)&M[e] = *(uint4*)tmp;
    }
}

// ---------------- 4. prep: x fp32 -> bf16 (ch<128 transposed [w][h]) ----------------
__global__ void prep(const float* __restrict__ x, u16* __restrict__ xb) {
    int tile = blockIdx.x;          // 0..15
    int mat = blockIdx.y;           // 0..1023
    int t = threadIdx.x;
    const float* xm = x + (size_t)mat * 65536u;
    u16* xo = xb + (size_t)mat * 65536u;
    __shared__ float lt[64][65];
    if ((mat & 255) >= 128) {       // WC half: straight cast
        int base = tile * 4096 + t * 16;
#pragma unroll
        for (int q = 0; q < 4; q++) {
            float4 v = *(const float4*)&xm[base + q * 4];
            ushort4 o; o.x = f2bf(v.x); o.y = f2bf(v.y); o.z = f2bf(v.z); o.w = f2bf(v.w);
            *(ushort4*)&xo[base + q * 4] = o;
        }
    } else {                        // HC half: 64x64 tiled transpose
        int w0 = (tile & 3) * 64, h0 = (tile >> 2) * 64;
        int rh = t >> 2, cc = (t & 3) * 16;
#pragma unroll
        for (int q = 0; q < 4; q++) {
            float4 v = *(const float4*)&xm[(h0 + rh) * 256 + w0 + cc + q * 4];
            lt[rh][cc + q * 4 + 0] = v.x; lt[rh][cc + q * 4 + 1] = v.y;
            lt[rh][cc + q * 4 + 2] = v.z; lt[rh][cc + q * 4 + 3] = v.w;
        }
        __syncthreads();
        u16 tmp[16];
#pragma unroll
        for (int j = 0; j < 16; j++) tmp[j] = f2bf(lt[cc + j][rh]);
#pragma unroll
        for (int q = 0; q < 4; q++)
            *(ushort4*)&xo[(w0 + rh) * 256 + h0 + cc + q * 4] = *(ushort4*)&tmp[q * 4];
    }
}

// ---------------- 5. gating GEMMs (bf16 MFMA, single-buffer K-loop) ----------------
// HC (br=0): Y = M_c @ X    (A = circulant rows m, B = x^T rows n)
// WC (br=1): Y = X @ M_c    (A = x rows m,         B = circulant rows n)
__global__ __launch_bounds__(256) void gate_gemm(
    const u16* __restrict__ xb, const u16* __restrict__ circ,
    u16* __restrict__ y, float* __restrict__ ws)
{
    const int tile = blockIdx.x, c = blockIdx.y, zb = blockIdx.z;
    const int b = zb >> 1, br = zb & 1;
    const int m0 = (tile >> 1) * 128, n0 = (tile & 1) * 128;
    const int t = threadIdx.x, lane = t & 63, w = t >> 6;
    const int ch = br * 128 + c;

    const u16* Mbase = circ + (size_t)ch * 65536u;
    const u16* Xbase = xb + (size_t)(b * 256 + ch) * 65536u;
    const int rM0 = br ? n0 : m0;
    const int rX0 = br ? m0 : n0;

    __shared__ u16 ldsM[4096];
    __shared__ u16 ldsX[4096];

    const int s1 = t + 256;
    const int kq0 = t >> 7, r0s = t & 127;
    const int kq1 = s1 >> 7, r1s = s1 & 127;
    const u16* gM0 = Mbase + (rM0 + r0s) * 256 + kq0 * 8;
    const u16* gM1 = Mbase + (rM0 + r1s) * 256 + kq1 * 8;
    const u16* gX0 = Xbase + (rX0 + r0s) * 256 + kq0 * 8;
    const u16* gX1 = Xbase + (rX0 + r1s) * 256 + kq1 * 8;
    u16* lM0 = &ldsM[(t & 192) * 8];
    u16* lM1 = &ldsM[((t & 192) + 256) * 8];
    u16* lX0 = &ldsX[(t & 192) * 8];
    u16* lX1 = &ldsX[((t & 192) + 256) * 8];

    floatx4 acc[4][4];
#pragma unroll
    for (int i = 0; i < 4; i++)
#pragma unroll
        for (int j = 0; j < 4; j++) acc[i][j] = (floatx4){0.f, 0.f, 0.f, 0.f};

    const int wm = (w & 1) * 64, wn = (w >> 1) * 64;
    const int fr = lane & 15, fq = lane >> 4;
    const u16* aB = br ? ldsX : ldsM;
    const u16* bB = br ? ldsM : ldsX;

    for (int k0 = 0; k0 < 256; k0 += 32) {
        gload_lds16(gM0, lM0); gload_lds16(gM1, lM1);
        gload_lds16(gX0, lX0); gload_lds16(gX1, lX1);
        gM0 += 32; gM1 += 32; gX0 += 32; gX1 += 32;
        __syncthreads();
        short8 aF[4], bF[4];
#pragma unroll
        for (int i = 0; i < 4; i++) aF[i] = *(const short8*)&aB[(fq * 128 + wm + i * 16 + fr) * 8];
#pragma unroll
        for (int j = 0; j < 4; j++) bF[j] = *(const short8*)&bB[(fq * 128 + wn + j * 16 + fr) * 8];
#pragma unroll
        for (int i = 0; i < 4; i++)
#pragma unroll
            for (int j = 0; j < 4; j++)
                acc[i][j] = __builtin_amdgcn_mfma_f32_16x16x32_bf16(aF[i], bF[j], acc[i][j], 0, 0, 0);
        __syncthreads();
    }

    // epilogue: bf16 y + channel sum
    size_t ybase = (size_t)(b * 256 + ch) * 65536u;
    float lsum = 0.f;
#pragma unroll
    for (int i = 0; i < 4; i++)
#pragma unroll
        for (int r = 0; r < 4; r++) {
            int row = m0 + wm + i * 16 + fq * 4 + r;
            size_t rb = ybase + (size_t)row * 256;
#pragma unroll
            for (int j = 0; j < 4; j++) {
                float v = acc[i][j][r];
                lsum += v;
                y[rb + n0 + wn + j * 16 + fr] = f2bf(v);
            }
        }
    for (int off = 32; off; off >>= 1) lsum += __shfl_down(lsum, off, 64);
    __shared__ float wsum[4];
    if (lane == 0) wsum[w] = lsum;
    __syncthreads();
    if (t == 0) atomicAdd(ws + WS_P + b * 256 + ch, wsum[0] + wsum[1] + wsum[2] + wsum[3]);
}

// ---------------- 6. attention scales + A_w = lc_w * s (bf16) ----------------
__global__ void attn_kernel(const float* __restrict__ ca_w1, const float* __restrict__ ca_b1,
                            const float* __restrict__ ca_dw, const float* __restrict__ ca_db,
                            const float* __restrict__ lc_w, float* ws, u16* __restrict__ aw) {
    int b = blockIdx.x, o = threadIdx.x;
    __shared__ float pm[256];
    __shared__ float sl[256];
    pm[o] = ws[WS_P + b * 256 + o] * (1.0f / 65536.0f);
    __syncthreads();
    float acc = ca_b1[o];
    for (int c2 = 0; c2 < 256; c2++) acc += ca_w1[o * 256 + c2] * pm[c2];
    float q = gelu_f(acc);
    float tv = q * ca_dw[o * 9 + 4] + ca_db[o];
    float s = 1.0f / (1.0f + expf(-tv));
    ws[WS_S + b * 256 + o] = s;
    sl[o] = s;
    __syncthreads();
    u16* awb = aw + b * 65536;
    for (int row = 0; row < 256; row++)
        awb[row * 256 + o] = f2bf(lc_w[row * 256 + o] * sl[o]);
}

// ---------------- 7. y -> y^T (bf16) ----------------
__global__ void ytrans(const u16* __restrict__ y, u16* __restrict__ yt) {
    int pt = blockIdx.x, ct = blockIdx.y, b = blockIdx.z;
    const u16* yb = y + (size_t)b * 16777216u;
    u16* ytb = yt + (size_t)b * 16777216u;
    int p0 = pt * 64, c0 = ct * 64;
    __shared__ u16 lt[64][74];   // 37-dword pitch: conflict-lite
    int t = threadIdx.x;
    int rr = t >> 3, pc = (t & 7) * 8;
#pragma unroll
    for (int it = 0; it < 2; it++) {
        int row = rr + it * 32;
        ushort4 a0 = *(const ushort4*)&yb[(size_t)(c0 + row) * 65536u + p0 + pc];
        ushort4 a1 = *(const ushort4*)&yb[(size_t)(c0 + row) * 65536u + p0 + pc + 4];
        lt[row][pc + 0] = a0.x; lt[row][pc + 1] = a0.y; lt[row][pc + 2] = a0.z; lt[row][pc + 3] = a0.w;
        lt[row][pc + 4] = a1.x; lt[row][pc + 5] = a1.y; lt[row][pc + 6] = a1.z; lt[row][pc + 7] = a1.w;
    }
    __syncthreads();
#pragma unroll
    for (int it = 0; it < 2; it++) {
        int row = rr + it * 32;       // p-rel
        u16 tmp[8];
#pragma unroll
        for (int j = 0; j < 8; j++) tmp[j] = lt[pc + j][row];
        *(uint4*)&ytb[(size_t)(p0 + row) * 256 + c0 + pc] = *(uint4*)tmp;
    }
}

// ---------------- 8. 1x1 conv GEMM + BN + GELU + residual ----------------
// Epilogue via LDS transpose: float4 x loads (prefetched) + float4 out stores.
__global__ __launch_bounds__(256) void conv_gemm(
    const float* __restrict__ x, const u16* __restrict__ aw, const u16* __restrict__ yt,
    const float* __restrict__ bn_g, const float* __restrict__ bn_b,
    const float* __restrict__ bn_m, const float* __restrict__ bn_v,
    float* __restrict__ out)
{
    const int m0 = blockIdx.x * 128;      // o
    const int n0 = blockIdx.y * 128;      // p
    const int b = blockIdx.z;
    const int t = threadIdx.x, lane = t & 63, w = t >> 6;

    const u16* Abase = aw + (size_t)b * 65536u;
    const u16* Bbase = yt + (size_t)b * 16777216u;

    // union: K-loop staging (2 x 8192 B) / epilogue fp32 chunk (32 x 130 x 4 = 16640 B)
    __shared__ __align__(16) char smem[16640];
    u16* ldsA = (u16*)smem;
    u16* ldsB = (u16*)(smem + 8192);
    float* ef = (float*)smem;

    const int s1 = t + 256;
    const int kq0 = t >> 7, r0s = t & 127;
    const int kq1 = s1 >> 7, r1s = s1 & 127;
    const u16* gA0 = Abase + (m0 + r0s) * 256 + kq0 * 8;
    const u16* gA1 = Abase + (m0 + r1s) * 256 + kq1 * 8;
    const u16* gB0 = Bbase + (size_t)(n0 + r0s) * 256 + kq0 * 8;
    const u16* gB1 = Bbase + (size_t)(n0 + r1s) * 256 + kq1 * 8;
    u16* lA0 = &ldsA[(t & 192) * 8];
    u16* lA1 = &ldsA[((t & 192) + 256) * 8];
    u16* lB0 = &ldsB[(t & 192) * 8];
    u16* lB1 = &ldsB[((t & 192) + 256) * 8];

    floatx4 acc[4][4];
#pragma unroll
    for (int i = 0; i < 4; i++)
#pragma unroll
        for (int j = 0; j < 4; j++) acc[i][j] = (floatx4){0.f, 0.f, 0.f, 0.f};

    const int wm = (w & 1) * 64, wn = (w >> 1) * 64;
    const int fr = lane & 15, fq = lane >> 4;

    for (int k0 = 0; k0 < 256; k0 += 32) {
        gload_lds16(gA0, lA0); gload_lds16(gA1, lA1);
        gload_lds16(gB0, lB0); gload_lds16(gB1, lB1);
        gA0 += 32; gA1 += 32; gB0 += 32; gB1 += 32;
        __syncthreads();
        short8 aF[4], bF[4];
#pragma unroll
        for (int i = 0; i < 4; i++) aF[i] = *(const short8*)&ldsA[(fq * 128 + wm + i * 16 + fr) * 8];
#pragma unroll
        for (int j = 0; j < 4; j++) bF[j] = *(const short8*)&ldsB[(fq * 128 + wn + j * 16 + fr) * 8];
#pragma unroll
        for (int i = 0; i < 4; i++)
#pragma unroll
            for (int j = 0; j < 4; j++)
                acc[i][j] = __builtin_amdgcn_mfma_f32_16x16x32_bf16(aF[i], bF[j], acc[i][j], 0, 0, 0);
        __syncthreads();
    }

    // ---- epilogue: 4 chunks of 32 rows x 128 cols through LDS ----
    const int lcol = (t & 31) * 4;        // 0..124, float4 column
    const int lrow0 = t >> 5;             // 0..7
#pragma unroll
    for (int cc = 0; cc < 4; cc++) {
        const int obase = m0 + cc * 32;
        // prefetch x (float4, coalesced) — latency hides under LDS write + barrier
        float4 xv[4];
#pragma unroll
        for (int ps = 0; ps < 4; ps++) {
            int o = obase + lrow0 + ps * 8;
            xv[ps] = *(const float4*)&x[(size_t)(b * 256 + o) * 65536u + n0 + lcol];
        }
        // acc -> LDS (2 of 4 waves own this 32-row chunk); pitch 130 -> 2-way banks (free)
        if (wm == ((cc >= 2) ? 64 : 0)) {
            const int ib = (cc & 1) * 2;
#pragma unroll
            for (int ii = 0; ii < 2; ii++) {
                const int i = ib + ii;
#pragma unroll
                for (int r = 0; r < 4; r++) {
                    int rl = (wm + i * 16 + fq * 4 + r) - cc * 32;  // 0..31
#pragma unroll
                    for (int j = 0; j < 4; j++)
                        ef[rl * 130 + wn + j * 16 + fr] = acc[i][j][r];
                }
            }
        }
        __syncthreads();
#pragma unroll
        for (int ps = 0; ps < 4; ps++) {
            int rl = lrow0 + ps * 8;
            int o = obase + rl;
            float inv = bn_g[o] * rsqrtf(bn_v[o] + 1e-5f);
            float beta = bn_b[o] - bn_m[o] * inv;
            float4 a = *(float4*)&ef[rl * 130 + lcol];
            float4 ov;
            ov.x = xv[ps].x + gelu_f(a.x * inv + beta);
            ov.y = xv[ps].y + gelu_f(a.y * inv + beta);
            ov.z = xv[ps].z + gelu_f(a.z * inv + beta);
            ov.w = xv[ps].w + gelu_f(a.w * inv + beta);
            *(float4*)&out[(size_t)(b * 256 + o) * 65536u + n0 + lcol] = ov;
        }
        if (cc < 3) __syncthreads();       // protect LDS before next chunk overwrites
    }
}

extern "C" void kernel_launch(void* const* d_in, const int* in_sizes, int n_in,
                              void* d_out, int out_size, void* d_ws, size_t ws_size,
                              hipStream_t stream) {
    const float* x = (const float*)d_in[0];
    MlpW m[4];
    for (int j = 0; j < 4; j++) {
        m[j].w1 = (const float*)d_in[1 + 6 * j + 0];
        m[j].b1 = (const float*)d_in[1 + 6 * j + 1];
        m[j].w2 = (const float*)d_in[1 + 6 * j + 2];
        m[j].b2 = (const float*)d_in[1 + 6 * j + 3];
        m[j].w3 = (const float*)d_in[1 + 6 * j + 4];
        m[j].b3 = (const float*)d_in[1 + 6 * j + 5];
    }
    const float* ca_w1 = (const float*)d_in[25];
    const float* ca_b1 = (const float*)d_in[26];
    const float* ca_dw = (const float*)d_in[27];
    const float* ca_db = (const float*)d_in[28];
    const float* lc_w  = (const float*)d_in[29];
    const float* bn_g  = (const float*)d_in[30];
    const float* bn_b  = (const float*)d_in[31];
    const float* bn_m  = (const float*)d_in[32];
    const float* bn_v  = (const float*)d_in[33];

    char* wsb = (char*)d_ws;
    float* ws = (float*)d_ws;
    u16* ybf  = (u16*)(wsb + Y0_B);
    u16* aw   = (u16*)(wsb + AW0_B);
    u16* circ = (u16*)(wsb + CIRC0_B);
    u16* xbb  = (u16*)(wsb + XB0_B);
    u16* yt   = (u16*)(wsb + YT0_B);
    float* out = (float*)d_out;

    hipLaunchKernelGGL(mlp_kernel, dim3(4), dim3(256), 0, stream, m[0], m[1], m[2], m[3], ws);
    hipLaunchKernelGGL(gatek_kernel, dim3(256), dim3(256), 0, stream, ws);
    hipLaunchKernelGGL(circmat, dim3(256), dim3(256), 0, stream, ws, circ);
    hipLaunchKernelGGL(prep, dim3(16, 1024), dim3(256), 0, stream, x, xbb);
    hipMemsetAsync(ws + WS_P, 0, 1024 * sizeof(float), stream);
    hipLaunchKernelGGL(gate_gemm, dim3(4, 128, 8), dim3(256), 0, stream, xbb, circ, ybf, ws);
    hipLaunchKernelGGL(attn_kernel, dim3(4), dim3(256), 0, stream,
                       ca_w1, ca_b1, ca_dw, ca_db, lc_w, ws, aw);
    hipLaunchKernelGGL(ytrans, dim3(1024, 4, 4), dim3(256), 0, stream, ybf, yt);
    hipLaunchKernelGGL(conv_gemm, dim3(2, 512, 4), dim3(256), 0, stream,
                       x, aw, yt, bn_g, bn_b, bn_m, bn_v, out);
}